// Round 1
// baseline (13523.111 us; speedup 1.0000x reference)
//
#include <hip/hip_runtime.h>
#include <hip/hip_bf16.h>

// LSTM stack B=32, T=512, H=1024, L=2.
// Structure:
//   pack_x     : x fp32 -> bf16 [B*T,1024]
//   pack_w     : Wx0,Wx1,Wh0,Wh1 -> Wp[4][4096][1024] bf16, transposed (N-major)
//                with gate-column permutation p = w*16 + gate*4 + c  (w=wg id)
//   pack_misc  : permuted bias + zero the grid-barrier counters
//   gemm_zx    : Zx[l] = inp @ Wx[l] + b[l]  (bf16 MFMA, 128x128x64 tiles),
//                output bf16 rows t*32+b, cols permuted
//   lstm_seq   : persistent 256-wg kernel, 512 steps, custom grid barrier per
//                step; wg owns h cols [4w..4w+4), Wh slice resident in LDS,
//                B-fragments hoisted to registers, c-state in LDS.

typedef __attribute__((ext_vector_type(8))) short short8;
typedef __attribute__((ext_vector_type(4))) float f32x4;

__device__ __forceinline__ unsigned short f2bu(float f) {
    __hip_bfloat16 h = __float2bfloat16(f);
    return *(unsigned short*)&h;
}
__device__ __forceinline__ float b2f(unsigned short u) {
    __hip_bfloat16 h = *(__hip_bfloat16*)&u;
    return __bfloat162float(h);
}

// ---------------------------------------------------------------- pack_x
__global__ __launch_bounds__(256) void pack_x(const float* __restrict__ x,
                                              unsigned short* __restrict__ xb) {
    int i = blockIdx.x * 256 + threadIdx.x;     // 4,194,304 float4 groups
    float4 v = ((const float4*)x)[i];
    ushort4 o;
    o.x = f2bu(v.x); o.y = f2bu(v.y); o.z = f2bu(v.z); o.w = f2bu(v.w);
    ((ushort4*)xb)[i] = o;
}

// ---------------------------------------------------------------- pack_w
// Wp[mi][p][k], p = w*16 + gate*4 + c  <->  orig col = gate*1024 + w*4 + c
__global__ __launch_bounds__(256) void pack_w(const float* __restrict__ Wx,
                                              const float* __restrict__ Wh,
                                              unsigned short* __restrict__ Wp) {
    __shared__ float tile[32][257];
    int mi = blockIdx.x >> 9;          // 0..3
    int rem = blockIdx.x & 511;
    int kb = rem >> 4;                 // 0..31  (32 k-rows each)
    int cb = rem & 15;                 // 0..15  (256 cols each)
    const float* src = (mi < 2) ? (Wx + (size_t)mi * 4194304)
                                : (Wh + (size_t)(mi - 2) * 4194304);
    int tid = threadIdx.x;
    // coalesced read 32x256 fp32 tile
    for (int p = 0; p < 8; ++p) {
        int row = p * 4 + (tid >> 6);
        int col4 = (tid & 63) * 4;
        float4 v = *(const float4*)(src + (size_t)(kb * 32 + row) * 4096 + cb * 256 + col4);
        tile[row][col4 + 0] = v.x; tile[row][col4 + 1] = v.y;
        tile[row][col4 + 2] = v.z; tile[row][col4 + 3] = v.w;
    }
    __syncthreads();
    // each thread owns one original column, writes 32 contiguous k as bf16
    int j = tid;
    int oc = cb * 256 + j;
    int gate = oc >> 10, w = (oc >> 2) & 255, c4 = oc & 3;
    int n = gate * 4 + c4;
    unsigned short* dst = Wp + (size_t)mi * 4194304 + (size_t)w * 16384 + n * 1024 + kb * 32;
    for (int k = 0; k < 32; ++k) dst[k] = f2bu(tile[k][j]);
}

// ---------------------------------------------------------------- pack_misc
__global__ __launch_bounds__(256) void pack_misc(const float* __restrict__ b,
                                                 float* __restrict__ biasp,
                                                 unsigned* __restrict__ bars) {
    int i = blockIdx.x * 256 + threadIdx.x;
    if (i < 8192) {
        int l = i >> 12, p = i & 4095;
        int w = p >> 4, q = p & 15, gate = q >> 2, c = q & 3;
        biasp[i] = b[l * 4096 + gate * 1024 + w * 4 + c];
    }
    if (i < 2048) bars[i] = 0u;   // two 4KB barrier areas
}

// ---------------------------------------------------------------- gemm_zx
// C[r][p] = sum_k A[r][k] * Bt[p][k]  + bias[p], bf16 in, bf16 out
// scatter=1: out row = (r&511)*32 + (r>>9)   (phase 1: A rows are b*512+t)
__global__ __launch_bounds__(256) void gemm_zx(const unsigned short* __restrict__ A,
                                               const unsigned short* __restrict__ Bt,
                                               const float* __restrict__ biasp,
                                               unsigned short* __restrict__ Zx,
                                               int scatter) {
    __shared__ unsigned short Ash[128 * 72];   // stride 72 halves: b128 at bank floor
    __shared__ unsigned short Bsh[128 * 72];
    int tid = threadIdx.x;
    int bn = blockIdx.x & 31, bm = blockIdx.x >> 5;
    int L = tid & 63, wv = tid >> 6;
    int wm = (wv >> 1) * 64, wn = (wv & 1) * 64;
    f32x4 acc[4][4];
    for (int mi = 0; mi < 4; ++mi)
        for (int ni = 0; ni < 4; ++ni)
            acc[mi][ni] = (f32x4){0.f, 0.f, 0.f, 0.f};
    const int rs = tid >> 3;    // staging row group 0..31
    const int ch = tid & 7;     // 16B chunk 0..7
    for (int kt = 0; kt < 16; ++kt) {
        int k0 = kt * 64;
        __syncthreads();
#pragma unroll
        for (int it = 0; it < 4; ++it) {
            int r = it * 32 + rs;
            short8 av = *(const short8*)(A + (size_t)(bm * 128 + r) * 1024 + k0 + ch * 8);
            short8 bv = *(const short8*)(Bt + (size_t)(bn * 128 + r) * 1024 + k0 + ch * 8);
            *(short8*)(Ash + r * 72 + ch * 8) = av;
            *(short8*)(Bsh + r * 72 + ch * 8) = bv;
        }
        __syncthreads();
#pragma unroll
        for (int ks = 0; ks < 2; ++ks) {
            int ko = ks * 32 + (L >> 4) * 8;
            short8 af[4], bfv[4];
#pragma unroll
            for (int i = 0; i < 4; ++i)
                af[i] = *(const short8*)(Ash + (wm + i * 16 + (L & 15)) * 72 + ko);
#pragma unroll
            for (int i = 0; i < 4; ++i)
                bfv[i] = *(const short8*)(Bsh + (wn + i * 16 + (L & 15)) * 72 + ko);
#pragma unroll
            for (int mi = 0; mi < 4; ++mi)
#pragma unroll
                for (int ni = 0; ni < 4; ++ni)
                    acc[mi][ni] = __builtin_amdgcn_mfma_f32_16x16x32_bf16(
                        af[mi], bfv[ni], acc[mi][ni], 0, 0, 0);
        }
    }
    // epilogue: C/D layout col=lane&15, row=(lane>>4)*4+i
#pragma unroll
    for (int mi = 0; mi < 4; ++mi) {
        int gr0 = bm * 128 + wm + mi * 16 + (L >> 4) * 4;
#pragma unroll
        for (int i = 0; i < 4; ++i) {
            int gr = gr0 + i;
            int outrow = scatter ? ((gr & 511) * 32 + (gr >> 9)) : gr;
#pragma unroll
            for (int ni = 0; ni < 4; ++ni) {
                int col = bn * 128 + wn + ni * 16 + (L & 15);
                float v = acc[mi][ni][i] + biasp[col];
                Zx[(size_t)outrow * 4096 + col] = f2bu(v);
            }
        }
    }
}

// ---------------------------------------------------------------- grid barrier
// two-level: 8 group counters (32 wgs each) -> root -> generation flag
__device__ __forceinline__ void grid_barrier(unsigned* bar) {
    __syncthreads();
    if (threadIdx.x == 0) {
        unsigned* grp = bar + ((blockIdx.x >> 5) * 32);
        unsigned* root = bar + 512;
        unsigned* gen = bar + 544;
        unsigned g = __hip_atomic_load(gen, __ATOMIC_RELAXED, __HIP_MEMORY_SCOPE_AGENT);
        unsigned p = __hip_atomic_fetch_add(grp, 1u, __ATOMIC_ACQ_REL, __HIP_MEMORY_SCOPE_AGENT);
        if (p == 31u) {
            __hip_atomic_store(grp, 0u, __ATOMIC_RELAXED, __HIP_MEMORY_SCOPE_AGENT);
            unsigned q = __hip_atomic_fetch_add(root, 1u, __ATOMIC_ACQ_REL, __HIP_MEMORY_SCOPE_AGENT);
            if (q == 7u) {
                __hip_atomic_store(root, 0u, __ATOMIC_RELAXED, __HIP_MEMORY_SCOPE_AGENT);
                __hip_atomic_store(gen, g + 1u, __ATOMIC_RELEASE, __HIP_MEMORY_SCOPE_AGENT);
            }
        }
        while (__hip_atomic_load(gen, __ATOMIC_RELAXED, __HIP_MEMORY_SCOPE_AGENT) == g)
            __builtin_amdgcn_s_sleep(2);
        (void)__hip_atomic_load(gen, __ATOMIC_ACQUIRE, __HIP_MEMORY_SCOPE_AGENT);
    }
    __syncthreads();
}

// ---------------------------------------------------------------- lstm_seq
// 256 wgs x 256 threads; wg owns h cols [4w, 4w+4) == packed gate cols [16w,16w+16)
__global__ __launch_bounds__(256) void lstm_seq(const unsigned short* __restrict__ Whp,
                                                const unsigned short* __restrict__ Zx,
                                                unsigned short* __restrict__ hbuf, // [2][32][1024]
                                                unsigned* __restrict__ bar,
                                                unsigned short* __restrict__ y_b,  // L0: y0b bf16 [T*B,1024]
                                                float* __restrict__ y_f,           // L1: y fp32 [B,T,1024]
                                                float* __restrict__ hf,
                                                float* __restrict__ cf) {
    __shared__ unsigned short Ws[16 * 1032];     // [n][k] padded (2064B rows)
    __shared__ float zs[4][32][16];              // per-wave K-partials
    __shared__ float cstate[32][4];
    int tid = threadIdx.x, wg = blockIdx.x;
    int L = tid & 63, wv = tid >> 6;

    // stage this wg's 16x1024 weight slice into LDS (once)
    const unsigned short* wsrc = Whp + (size_t)wg * 16384;
    for (int i = 0; i < 8; ++i) {
        int c = tid + i * 256;           // 0..2047 16B chunks
        int n = c >> 7, cc = c & 127;
        *(short8*)(Ws + n * 1032 + cc * 8) = *(const short8*)(wsrc + n * 1024 + cc * 8);
    }
    if (tid < 128) {
        cstate[tid >> 2][tid & 3] = 0.f;
        hbuf[32768 + wg * 128 + tid] = 0;   // h_{-1} = 0 in buffer 1
    }
    __syncthreads();

    // hoist the 8 B-fragments (constant over t): B[k][n], n=lane&15, k=quad*8+j
    short8 bfr[8];
    int ko = (L >> 4) * 8;
#pragma unroll
    for (int kst = 0; kst < 8; ++kst)
        bfr[kst] = *(const short8*)(Ws + (L & 15) * 1032 + wv * 256 + kst * 32 + ko);

    for (int t = 0; t < 512; ++t) {
        grid_barrier(bar);   // publishes h_{t-1} (and the zero-init at t=0)
        const unsigned short* hp = hbuf + ((t + 1) & 1) * 32768;
        f32x4 acc0 = {0.f, 0.f, 0.f, 0.f}, acc1 = {0.f, 0.f, 0.f, 0.f};
#pragma unroll
        for (int kst = 0; kst < 8; ++kst) {
            int k = wv * 256 + kst * 32 + ko;
            short8 a0 = *(const short8*)(hp + (L & 15) * 1024 + k);
            short8 a1 = *(const short8*)(hp + (16 + (L & 15)) * 1024 + k);
            acc0 = __builtin_amdgcn_mfma_f32_16x16x32_bf16(a0, bfr[kst], acc0, 0, 0, 0);
            acc1 = __builtin_amdgcn_mfma_f32_16x16x32_bf16(a1, bfr[kst], acc1, 0, 0, 0);
        }
#pragma unroll
        for (int i = 0; i < 4; ++i) {
            zs[wv][(L >> 4) * 4 + i][L & 15] = acc0[i];
            zs[wv][16 + (L >> 4) * 4 + i][L & 15] = acc1[i];
        }
        __syncthreads();
        if (tid < 128) {
            int b = tid >> 2, c = tid & 3;
            float zi = 0, zf = 0, zg = 0, zo = 0;
#pragma unroll
            for (int w = 0; w < 4; ++w) {
                zi += zs[w][b][c];      zf += zs[w][b][4 + c];
                zg += zs[w][b][8 + c];  zo += zs[w][b][12 + c];
            }
            const unsigned short* zrow = Zx + (size_t)(t * 32 + b) * 4096 + wg * 16;
            zi += b2f(zrow[c]);     zf += b2f(zrow[4 + c]);
            zg += b2f(zrow[8 + c]); zo += b2f(zrow[12 + c]);
            float si = 1.f / (1.f + expf(-zi));
            float sf = 1.f / (1.f + expf(-zf));
            float so = 1.f / (1.f + expf(-zo));
            float cn = sf * cstate[b][c] + si * tanhf(zg);
            cstate[b][c] = cn;
            float h = so * tanhf(cn);
            int col = wg * 4 + c;
            hbuf[(t & 1) * 32768 + b * 1024 + col] = f2bu(h);
            if (y_b) y_b[(size_t)(t * 32 + b) * 1024 + col] = f2bu(h);
            if (y_f) y_f[(size_t)(b * 512 + t) * 1024 + col] = h;
            if (t == 511) {
                hf[b * 1024 + col] = h;
                cf[b * 1024 + col] = cn;
            }
        }
        // zs reuse is guarded by the grid_barrier's entry __syncthreads
    }
}

// ---------------------------------------------------------------- launch
extern "C" void kernel_launch(void* const* d_in, const int* in_sizes, int n_in,
                              void* d_out, int out_size, void* d_ws, size_t ws_size,
                              hipStream_t stream) {
    const float* x  = (const float*)d_in[0];
    const float* Wx = (const float*)d_in[1];
    const float* Wh = (const float*)d_in[2];
    const float* bb = (const float*)d_in[3];

    char* ws = (char*)d_ws;
    unsigned short* Wp  = (unsigned short*)ws;                          //  32MB: Wp[4][4096][1024]
    unsigned short* xb  = (unsigned short*)(ws + (32ull << 20));        //  32MB: xb / y0b (aliased)
    unsigned short* Zx  = (unsigned short*)(ws + (64ull << 20));        // 128MB: Zx bf16 [16384][4096]
    char* misc          = ws + (192ull << 20);
    float* biasp        = (float*)misc;                                 // 32KB
    unsigned* bar0      = (unsigned*)(misc + (64 << 10));               // 4KB
    unsigned* bar1      = bar0 + 1024;                                  // 4KB
    unsigned short* h0b = (unsigned short*)(misc + (128 << 10));        // 128KB
    unsigned short* h1b = (unsigned short*)(misc + (256 << 10));        // 128KB

    float* out = (float*)d_out;
    float* hf0 = out + 16777216;
    float* hf1 = hf0 + 32768;
    float* cf0 = out + 16777216 + 65536;
    float* cf1 = cf0 + 32768;

    pack_x<<<16384, 256, 0, stream>>>(x, xb);
    pack_w<<<2048, 256, 0, stream>>>(Wx, Wh, Wp);
    pack_misc<<<32, 256, 0, stream>>>(bb, biasp, bar0);

    // layer 0: Zx0 = x @ Wx0 + b0  (rows b*512+t -> scatter to t*32+b)
    gemm_zx<<<4096, 256, 0, stream>>>(xb, Wp, biasp, Zx, 1);
    lstm_seq<<<256, 256, 0, stream>>>(Wp + 2ull * 4194304, Zx, h0b, bar0,
                                      /*y_b=*/xb, /*y_f=*/nullptr, hf0, cf0);
    // layer 1: Zx1 = y0 @ Wx1 + b1  (rows already t*32+b)
    gemm_zx<<<4096, 256, 0, stream>>>(xb, Wp + 4194304, biasp + 4096, Zx, 0);
    lstm_seq<<<256, 256, 0, stream>>>(Wp + 3ull * 4194304, Zx, h1b, bar1,
                                      /*y_b=*/nullptr, /*y_f=*/out, hf1, cf1);
}

// Round 2
// 6997.923 us; speedup vs baseline: 1.9324x; 1.9324x over previous
//
#include <hip/hip_runtime.h>
#include <hip/hip_bf16.h>

// LSTM stack B=32, T=512, H=1024, L=2.  Round 2: fused persistent kernel.
//   pack_x     : x fp32 -> bf16 [B*T,1024]
//   pack_w     : Wx0 -> Wxp [4096 p][1024 k]  (p = w*32 + gate*8 + c, w=wg, c=hcol&7)
//                Wh0 -> Whp0 [4096 p][1024 k]
//                Wx1,Wh1 -> Wcat [4096 p][2048 k]  (k<1024 = Wx1, k>=1024 = Wh1)
//   pack_misc  : packed L0 bias + zero barrier flags + zero h exchange buffers
//   gemm_zx    : Zx0 = x @ Wx0 + b0, written per-wg-contiguous [128 w][512 t][32 b][32 q]
//   lstm_fused : 256 persistent wgs, 513 grid-barrier steps.
//                wgs   0..127: layer 0, wg owns h-cols [8w,8w+8) (32 gate cols), K=1024
//                wgs 128..255: layer 1 (runs one step behind), K=2048 over [y0; h1]
//                All cross-wg sync via RELAXED agent atomics (no L2 wb/inv storms).

typedef __attribute__((ext_vector_type(8))) short short8;
typedef __attribute__((ext_vector_type(4))) float f32x4;

__device__ __forceinline__ unsigned short f2bu(float f) {
    __hip_bfloat16 h = __float2bfloat16(f);
    return *(unsigned short*)&h;
}
__device__ __forceinline__ float b2f(unsigned short u) {
    __hip_bfloat16 h = *(__hip_bfloat16*)&u;
    return __bfloat162float(h);
}

union U16 { unsigned long long u[2]; short8 s; };

// 16B exchange-buffer read as two 8B relaxed agent atomics (bypass L1/L2 -> LLC)
__device__ __forceinline__ short8 ald16(const unsigned short* p) {
    U16 x;
    x.u[0] = __hip_atomic_load((unsigned long long*)p,       __ATOMIC_RELAXED, __HIP_MEMORY_SCOPE_AGENT);
    x.u[1] = __hip_atomic_load((unsigned long long*)(p + 4), __ATOMIC_RELAXED, __HIP_MEMORY_SCOPE_AGENT);
    return x.s;
}
__device__ __forceinline__ void ast8(unsigned short* p, unsigned long long v) {
    __hip_atomic_store((unsigned long long*)p, v, __ATOMIC_RELAXED, __HIP_MEMORY_SCOPE_AGENT);
}
__device__ __forceinline__ f32x4 mfma16(short8 a, short8 b, f32x4 c) {
    return __builtin_amdgcn_mfma_f32_16x16x32_bf16(a, b, c, 0, 0, 0);
}

// ---------------------------------------------------------------- pack_x
__global__ __launch_bounds__(256) void pack_x(const float* __restrict__ x,
                                              unsigned short* __restrict__ xb) {
    int i = blockIdx.x * 256 + threadIdx.x;     // 4,194,304 float4 groups
    float4 v = ((const float4*)x)[i];
    ushort4 o;
    o.x = f2bu(v.x); o.y = f2bu(v.y); o.z = f2bu(v.z); o.w = f2bu(v.w);
    ((ushort4*)xb)[i] = o;
}

// ---------------------------------------------------------------- pack_w
// p = w*32 + gate*8 + c   <->  orig col = gate*1024 + w*8 + c
__global__ __launch_bounds__(256) void pack_w(const float* __restrict__ Wx,
                                              const float* __restrict__ Wh,
                                              unsigned short* __restrict__ Wxp,
                                              unsigned short* __restrict__ Whp0,
                                              unsigned short* __restrict__ Wcat) {
    __shared__ float tile[32][257];
    int mi = blockIdx.x >> 9;          // 0:Wx0 1:Wx1 2:Wh0 3:Wh1
    int rem = blockIdx.x & 511;
    int kb = rem >> 4;                 // 0..31  (32 k-rows each)
    int cb = rem & 15;                 // 0..15  (256 cols each)
    const float* src = (mi == 0) ? Wx : (mi == 1) ? (Wx + 4194304)
                     : (mi == 2) ? Wh : (Wh + 4194304);
    int tid = threadIdx.x;
    for (int pphase = 0; pphase < 8; ++pphase) {
        int row = pphase * 4 + (tid >> 6);
        int col4 = (tid & 63) * 4;
        float4 v = *(const float4*)(src + (size_t)(kb * 32 + row) * 4096 + cb * 256 + col4);
        tile[row][col4 + 0] = v.x; tile[row][col4 + 1] = v.y;
        tile[row][col4 + 2] = v.z; tile[row][col4 + 3] = v.w;
    }
    __syncthreads();
    int j = tid;
    int oc = cb * 256 + j;
    int gate = oc >> 10, hc = oc & 1023, w = hc >> 3, c = hc & 7;
    int p = w * 32 + gate * 8 + c;
    unsigned short* dst;
    if (mi == 0)      dst = Wxp  + (size_t)p * 1024 + kb * 32;
    else if (mi == 2) dst = Whp0 + (size_t)p * 1024 + kb * 32;
    else if (mi == 1) dst = Wcat + (size_t)p * 2048 + kb * 32;
    else              dst = Wcat + (size_t)p * 2048 + 1024 + kb * 32;
    for (int k = 0; k < 32; ++k) dst[k] = f2bu(tile[k][j]);
}

// ---------------------------------------------------------------- pack_misc
__global__ __launch_bounds__(256) void pack_misc(const float* __restrict__ b,
                                                 float* __restrict__ biasp,
                                                 unsigned* __restrict__ bars,
                                                 unsigned* __restrict__ hz) {
    int i = blockIdx.x * 256 + threadIdx.x;   // grid 256 -> 65536
    if (i < 4096) {
        int w = i >> 5, q = i & 31, gate = q >> 3, c = q & 7;
        biasp[i] = b[gate * 1024 + w * 8 + c];
    }
    if (i < 1024) bars[i] = 0u;
    hz[i] = 0u;   // 65536 uints = 256KB: both h0buf[2] and h1buf[2]
}

// ---------------------------------------------------------------- gemm_zx
// C[r][p] = sum_k A[r][k] * Bt[p][k] + biasp[p]; A rows r = b*512+t.
// Output packed: Zx[((p>>5)*512 + t)*32 + b][32] + (p&31)
__global__ __launch_bounds__(256) void gemm_zx(const unsigned short* __restrict__ A,
                                               const unsigned short* __restrict__ Bt,
                                               const float* __restrict__ biasp,
                                               unsigned short* __restrict__ Zx) {
    __shared__ unsigned short Ash[128 * 72];
    __shared__ unsigned short Bsh[128 * 72];
    int tid = threadIdx.x;
    int bn = blockIdx.x & 31, bm = blockIdx.x >> 5;
    int L = tid & 63, wv = tid >> 6;
    int wm = (wv >> 1) * 64, wn = (wv & 1) * 64;
    f32x4 acc[4][4];
    for (int mi = 0; mi < 4; ++mi)
        for (int ni = 0; ni < 4; ++ni)
            acc[mi][ni] = (f32x4){0.f, 0.f, 0.f, 0.f};
    const int rs = tid >> 3;
    const int ch = tid & 7;
    for (int kt = 0; kt < 16; ++kt) {
        int k0 = kt * 64;
        __syncthreads();
#pragma unroll
        for (int it = 0; it < 4; ++it) {
            int r = it * 32 + rs;
            short8 av = *(const short8*)(A + (size_t)(bm * 128 + r) * 1024 + k0 + ch * 8);
            short8 bv = *(const short8*)(Bt + (size_t)(bn * 128 + r) * 1024 + k0 + ch * 8);
            *(short8*)(Ash + r * 72 + ch * 8) = av;
            *(short8*)(Bsh + r * 72 + ch * 8) = bv;
        }
        __syncthreads();
#pragma unroll
        for (int ks = 0; ks < 2; ++ks) {
            int ko = ks * 32 + (L >> 4) * 8;
            short8 af[4], bfv[4];
#pragma unroll
            for (int i = 0; i < 4; ++i)
                af[i] = *(const short8*)(Ash + (wm + i * 16 + (L & 15)) * 72 + ko);
#pragma unroll
            for (int i = 0; i < 4; ++i)
                bfv[i] = *(const short8*)(Bsh + (wn + i * 16 + (L & 15)) * 72 + ko);
#pragma unroll
            for (int mi = 0; mi < 4; ++mi)
#pragma unroll
                for (int ni = 0; ni < 4; ++ni)
                    acc[mi][ni] = mfma16(af[mi], bfv[ni], acc[mi][ni]);
        }
    }
#pragma unroll
    for (int mi = 0; mi < 4; ++mi) {
        int gr0 = bm * 128 + wm + mi * 16 + (L >> 4) * 4;
#pragma unroll
        for (int i = 0; i < 4; ++i) {
            int gr = gr0 + i;
            int bnat = gr >> 9, t = gr & 511;
#pragma unroll
            for (int ni = 0; ni < 4; ++ni) {
                int p = bn * 128 + wn + ni * 16 + (L & 15);
                float v = acc[mi][ni][i] + biasp[p];
                size_t addr = (((size_t)(p >> 5) * 512 + t) * 32 + bnat) * 32 + (p & 31);
                Zx[addr] = f2bu(v);
            }
        }
    }
}

// ---------------------------------------------------------------- step MFMA
template<int LAY>
__device__ __forceinline__ void step_mfma(const unsigned short* __restrict__ h0p,
                                          const unsigned short* __restrict__ h1p,
                                          const short8 (&bfr)[2][16],
                                          int wv, int quad, int m_r,
                                          f32x4 (&acc)[2][2]) {
    constexpr int NK = LAY ? 16 : 8;
    constexpr int KW = LAY ? 512 : 256;
    const unsigned short* ap = (LAY && wv >= 2) ? h1p : h0p;
    int kbase = (LAY && wv >= 2) ? (wv * KW - 1024) : (wv * KW);
#pragma unroll
    for (int ks = 0; ks < NK; ++ks) {
        int ko = kbase + ks * 32 + quad * 8;
        short8 a0 = ald16(ap + m_r * 1024 + ko);
        short8 a1 = ald16(ap + (16 + m_r) * 1024 + ko);
        acc[0][0] = mfma16(a0, bfr[0][ks], acc[0][0]);
        acc[0][1] = mfma16(a0, bfr[1][ks], acc[0][1]);
        acc[1][0] = mfma16(a1, bfr[0][ks], acc[1][0]);
        acc[1][1] = mfma16(a1, bfr[1][ks], acc[1][1]);
    }
}

// ---------------------------------------------------------------- lstm_fused
__global__ __launch_bounds__(256, 1) void lstm_fused(
        const unsigned short* __restrict__ Whp0,   // [4096][1024]
        const unsigned short* __restrict__ Wcat,   // [4096][2048]
        const unsigned short* __restrict__ Zx,     // [128][512][32][32]
        const float* __restrict__ bias,            // original b [2][4096]
        unsigned short* __restrict__ h0buf,        // [2][32][1024]
        unsigned short* __restrict__ h1buf,        // [2][32][1024]
        unsigned* __restrict__ flags,              // [256]; gen copies at +320+r*32
        float* __restrict__ out) {
    __shared__ float zs[4][32][32];
    __shared__ unsigned long long zx8[256];        // 32x32 bf16 block
    __shared__ unsigned long long hl8[32];         // 32x8 bf16
    unsigned short* zxloc = (unsigned short*)zx8;
    unsigned short* hloc  = (unsigned short*)hl8;

    int tid = threadIdx.x, wgid = blockIdx.x;
    int lay = wgid >> 7, w = wgid & 127;
    int L = tid & 63, wv = tid >> 6;
    int m_r = L & 15, quad = L >> 4;
    int nk = lay ? 16 : 8;
    int K  = lay ? 2048 : 1024;

    // hoist B fragments from packed global weights (plain cached loads, once)
    short8 bfr[2][16];
    {
        const unsigned short* wb = lay ? (Wcat + (size_t)w * 32 * 2048)
                                       : (Whp0 + (size_t)w * 32 * 1024);
        for (int nt = 0; nt < 2; ++nt)
            for (int ks = 0; ks < nk; ++ks) {
                int n = nt * 16 + m_r;
                int k = wv * (K / 4) + ks * 32 + quad * 8;
                bfr[nt][ks] = *(const short8*)(wb + (size_t)n * K + k);
            }
    }
    // gate-thread mapping: tid -> (b, c)
    int gb = tid >> 3, gc = tid & 7;
    float bi0 = 0.f, bf0 = 0.f, bg0 = 0.f, bo0 = 0.f;
    if (lay) {
        bi0 = bias[4096 + 0 * 1024 + w * 8 + gc];
        bf0 = bias[4096 + 1 * 1024 + w * 8 + gc];
        bg0 = bias[4096 + 2 * 1024 + w * 8 + gc];
        bo0 = bias[4096 + 3 * 1024 + w * 8 + gc];
    }
    float creg = 0.f;

    for (int s = 0; s < 513; ++s) {
        int t = lay ? s - 1 : s;
        bool active = lay ? (s >= 1) : (s < 512);
        if (active) {
            const unsigned short* h0p = h0buf + ((s + 1) & 1) * 32768;
            const unsigned short* h1p = h1buf + ((s + 1) & 1) * 32768;
            if (!lay) {   // stage this step's Zx block (2KB contiguous) into LDS
                const unsigned long long* zb =
                    (const unsigned long long*)(Zx + ((size_t)w * 512 + t) * 1024);
                zx8[tid] = zb[tid];
            }
            f32x4 acc[2][2];
            for (int a = 0; a < 2; ++a)
                for (int bq = 0; bq < 2; ++bq)
                    acc[a][bq] = (f32x4){0.f, 0.f, 0.f, 0.f};
            if (lay) step_mfma<1>(h0p, h1p, bfr, wv, quad, m_r, acc);
            else     step_mfma<0>(h0p, h1p, bfr, wv, quad, m_r, acc);
#pragma unroll
            for (int mt = 0; mt < 2; ++mt)
#pragma unroll
                for (int nt = 0; nt < 2; ++nt)
#pragma unroll
                    for (int i = 0; i < 4; ++i)
                        zs[wv][mt * 16 + quad * 4 + i][nt * 16 + m_r] = acc[mt][nt][i];
        }
        __syncthreads();
        if (active) {
            float zi = bi0, zf = bf0, zg = bg0, zo = bo0;
#pragma unroll
            for (int v = 0; v < 4; ++v) {
                zi += zs[v][gb][gc];      zf += zs[v][gb][8 + gc];
                zg += zs[v][gb][16 + gc]; zo += zs[v][gb][24 + gc];
            }
            if (!lay) {
                zi += b2f(zxloc[gb * 32 + gc]);      zf += b2f(zxloc[gb * 32 + 8 + gc]);
                zg += b2f(zxloc[gb * 32 + 16 + gc]); zo += b2f(zxloc[gb * 32 + 24 + gc]);
            }
            float si = 1.f / (1.f + __expf(-zi));
            float sf = 1.f / (1.f + __expf(-zf));
            float so = 1.f / (1.f + __expf(-zo));
            float cn = sf * creg + si * tanhf(zg);
            creg = cn;
            float h = so * tanhf(cn);
            hloc[gb * 8 + gc] = f2bu(h);
            if (lay) {
                out[((size_t)gb * 512 + t) * 1024 + w * 8 + gc] = h;
                if (t == 511) {
                    out[16777216 + 32768 + gb * 1024 + w * 8 + gc] = h;
                    out[16777216 + 65536 + 32768 + gb * 1024 + w * 8 + gc] = cn;
                }
            } else if (t == 511) {
                out[16777216 + gb * 1024 + w * 8 + gc] = h;
                out[16777216 + 65536 + gb * 1024 + w * 8 + gc] = cn;
            }
        }
        __syncthreads();
        if (active && tid < 64) {   // publish h to exchange buffer (LLC-direct)
            int br = tid >> 1, half = tid & 1;
            unsigned long long v = *(unsigned long long*)(hloc + br * 8 + half * 4);
            unsigned short* dst = (lay ? h1buf : h0buf) + (s & 1) * 32768
                                  + br * 1024 + w * 8 + half * 4;
            ast8(dst, v);
        }
        // ---- grid barrier: relaxed-only, flag array + root poll + 8-way gen ----
        __syncthreads();   // drains each wave's vmcnt -> h stores are at LLC
        unsigned tgt = (unsigned)s + 1u;
        if (tid == 0)
            __hip_atomic_store(flags + wgid, tgt, __ATOMIC_RELAXED, __HIP_MEMORY_SCOPE_AGENT);
        if (wgid == 0 && tid < 64) {
            for (;;) {
                unsigned f0 = __hip_atomic_load(flags + tid,       __ATOMIC_RELAXED, __HIP_MEMORY_SCOPE_AGENT);
                unsigned f1 = __hip_atomic_load(flags + 64 + tid,  __ATOMIC_RELAXED, __HIP_MEMORY_SCOPE_AGENT);
                unsigned f2 = __hip_atomic_load(flags + 128 + tid, __ATOMIC_RELAXED, __HIP_MEMORY_SCOPE_AGENT);
                unsigned f3 = __hip_atomic_load(flags + 192 + tid, __ATOMIC_RELAXED, __HIP_MEMORY_SCOPE_AGENT);
                if (__all((f0 >= tgt) && (f1 >= tgt) && (f2 >= tgt) && (f3 >= tgt))) break;
                __builtin_amdgcn_s_sleep(2);
            }
            if (tid < 8)
                __hip_atomic_store(flags + 320 + tid * 32, tgt, __ATOMIC_RELAXED, __HIP_MEMORY_SCOPE_AGENT);
        }
        if (tid == 0) {
            unsigned* g = flags + 320 + (wgid & 7) * 32;
            while (__hip_atomic_load(g, __ATOMIC_RELAXED, __HIP_MEMORY_SCOPE_AGENT) < tgt)
                __builtin_amdgcn_s_sleep(2);
        }
        __syncthreads();
    }
}

// ---------------------------------------------------------------- launch
extern "C" void kernel_launch(void* const* d_in, const int* in_sizes, int n_in,
                              void* d_out, int out_size, void* d_ws, size_t ws_size,
                              hipStream_t stream) {
    const float* x  = (const float*)d_in[0];
    const float* Wx = (const float*)d_in[1];
    const float* Wh = (const float*)d_in[2];
    const float* bb = (const float*)d_in[3];

    char* ws = (char*)d_ws;
    unsigned short* Wxp  = (unsigned short*)ws;                       //  8MB [4096][1024]
    unsigned short* Whp0 = (unsigned short*)(ws + (8ull  << 20));     //  8MB [4096][1024]
    unsigned short* Wcat = (unsigned short*)(ws + (16ull << 20));     // 16MB [4096][2048]
    unsigned short* xb   = (unsigned short*)(ws + (32ull << 20));     // 32MB
    unsigned short* Zx   = (unsigned short*)(ws + (64ull << 20));     // 128MB
    char* misc           = ws + (192ull << 20);
    float* biasp         = (float*)misc;                              // 16KB
    unsigned* bars       = (unsigned*)(misc + (64 << 10));            // 4KB
    unsigned short* h0b  = (unsigned short*)(misc + (128 << 10));     // 128KB [2][32][1024]
    unsigned short* h1b  = (unsigned short*)(misc + (256 << 10));     // 128KB
    unsigned* hz         = (unsigned*)(misc + (128 << 10));           // both hbufs, 256KB

    float* out = (float*)d_out;

    pack_x<<<16384, 256, 0, stream>>>(x, xb);
    pack_w<<<2048, 256, 0, stream>>>(Wx, Wh, Wxp, Whp0, Wcat);
    pack_misc<<<256, 256, 0, stream>>>(bb, biasp, bars, hz);

    gemm_zx<<<4096, 256, 0, stream>>>(xb, Wxp, biasp, Zx);
    lstm_fused<<<256, 256, 0, stream>>>(Whp0, Wcat, Zx, bb, h0b, h1b, bars, out);
}